// Round 1
// baseline (564.325 us; speedup 1.0000x reference)
//
#include <hip/hip_runtime.h>
#include <hip/hip_bf16.h>
#include <cstddef>

typedef __attribute__((ext_vector_type(8))) short short8;
typedef __attribute__((ext_vector_type(4))) float f32x4;

#define D_MODEL 768
#define N_HEADS 4
#define HEAD_DIM 192
#define BATCH 4
#define SEQ 2048
#define M_ROWS (BATCH*SEQ)

__device__ __forceinline__ short f2bf(float f) {
  union { float f; unsigned u; } v; v.f = f;
  unsigned r = v.u + 0x7FFFu + ((v.u >> 16) & 1u);
  return (short)(r >> 16);
}

// ---------------- cast fp32 -> bf16, 8 elems/thread ----------------
__global__ __launch_bounds__(256) void cast_kernel(const float* __restrict__ src,
                                                   short* __restrict__ dst, int n8) {
  int i = blockIdx.x * 256 + threadIdx.x;
  if (i >= n8) return;
  const float4* s = (const float4*)src;
  float4 a = s[2 * i], b = s[2 * i + 1];
  short8 o;
  o[0] = f2bf(a.x); o[1] = f2bf(a.y); o[2] = f2bf(a.z); o[3] = f2bf(a.w);
  o[4] = f2bf(b.x); o[5] = f2bf(b.y); o[6] = f2bf(b.z); o[7] = f2bf(b.w);
  *(short8*)(dst + (size_t)i * 8) = o;
}

// ---------------- bf16 MFMA GEMM: C[M][N] = A[M][K] @ W[K][N] + bias ----------------
// MODE 0: write fp32 [M][N].  MODE 1: write bf16 split-head [B][H][S][Dh].
template <int MODE>
__global__ __launch_bounds__(256) void gemm_bf16(const short* __restrict__ A,
                                                 const short* __restrict__ W,
                                                 const float* __restrict__ bias,
                                                 void* __restrict__ out,
                                                 int M, int N, int K) {
  __shared__ short As[64][40];  // [m][k], stride 40 shorts = 80B (16B aligned, 2-way banks)
  __shared__ short Bs[64][40];  // [n][k] (transposed W tile)

  const int m0 = blockIdx.x * 64;
  const int n0 = blockIdx.y * 64;
  const int t = threadIdx.x;
  const int lane = t & 63, w = t >> 6;
  const int wr = w >> 1, wc = w & 1;
  const int lr = lane & 15, lg = lane >> 4;
  const int lk = lg * 8;

  f32x4 acc[2][2] = {};

  for (int k0 = 0; k0 < K; k0 += 32) {
    // stage A: 64x32 bf16, one short8 per thread
    {
      int row = t >> 2;
      int c8 = (t & 3) * 8;
      *(short8*)&As[row][c8] =
          *(const short8*)&A[(size_t)(m0 + row) * K + k0 + c8];
    }
    // stage B transposed: read W[k][n] coalesced, scatter to Bs[n][k]
    {
      int kk = t >> 3;
      int n8 = (t & 7) * 8;
      short8 wv = *(const short8*)&W[(size_t)(k0 + kk) * N + n0 + n8];
#pragma unroll
      for (int i = 0; i < 8; i++) Bs[n8 + i][kk] = wv[i];
    }
    __syncthreads();

    short8 af0 = *(const short8*)&As[wr * 32 + lr][lk];
    short8 af1 = *(const short8*)&As[wr * 32 + 16 + lr][lk];
    short8 bf0 = *(const short8*)&Bs[wc * 32 + lr][lk];
    short8 bf1 = *(const short8*)&Bs[wc * 32 + 16 + lr][lk];
    acc[0][0] = __builtin_amdgcn_mfma_f32_16x16x32_bf16(af0, bf0, acc[0][0], 0, 0, 0);
    acc[0][1] = __builtin_amdgcn_mfma_f32_16x16x32_bf16(af0, bf1, acc[0][1], 0, 0, 0);
    acc[1][0] = __builtin_amdgcn_mfma_f32_16x16x32_bf16(af1, bf0, acc[1][0], 0, 0, 0);
    acc[1][1] = __builtin_amdgcn_mfma_f32_16x16x32_bf16(af1, bf1, acc[1][1], 0, 0, 0);
    __syncthreads();
  }

#pragma unroll
  for (int i = 0; i < 2; i++)
#pragma unroll
    for (int j = 0; j < 2; j++)
#pragma unroll
      for (int r = 0; r < 4; r++) {
        int row = m0 + wr * 32 + i * 16 + lg * 4 + r;
        int col = n0 + wc * 32 + j * 16 + lr;
        float v = acc[i][j][r] + bias[col];
        if (MODE == 0) {
          ((float*)out)[(size_t)row * N + col] = v;
        } else {
          int bb = row >> 11, s = row & (SEQ - 1);
          int h = col / HEAD_DIM, d = col % HEAD_DIM;
          ((short*)out)[(((size_t)(bb * N_HEADS + h)) * SEQ + s) * HEAD_DIM + d] =
              f2bf(v);
        }
      }
}

// ---------------- flash-style causal attention ----------------
// Q,K,V: bf16 [B][H][S][Dh]; ctx: bf16 [B][S][H*Dh]
__global__ __launch_bounds__(256) void attn_kernel(const short* __restrict__ Q,
                                                   const short* __restrict__ Kg,
                                                   const short* __restrict__ Vg,
                                                   short* __restrict__ ctx) {
  const int qb = blockIdx.x;       // 0..31 (64 q-rows each)
  const int bh = blockIdx.y;       // 0..15
  const int b = bh >> 2, h = bh & 3;
  const int q0 = qb * 64;
  const size_t base = (size_t)bh * SEQ * HEAD_DIM;
  const short* Qp = Q + base;
  const short* Kp = Kg + base;
  const short* Vp = Vg + base;

  const int t = threadIdx.x;
  const int lane = t & 63, w = t >> 6;
  const int lr = lane & 15, lg = lane >> 4;

  __shared__ short Ks[32][200];      // [k][d], pad to 200 (400B rows)
  __shared__ short Vt[192][40];      // [d][k] transposed
  __shared__ short Ps[4][16][40];    // per-wave P tile [q][k]

  // Q fragments: 6 chunks of K=32 along Dh
  short8 qf[6];
#pragma unroll
  for (int c = 0; c < 6; c++)
    qf[c] = *(const short8*)&Qp[(size_t)(q0 + w * 16 + lr) * HEAD_DIM + c * 32 + lg * 8];

  f32x4 o[12] = {};
  float m_i[4], l_i[4];
#pragma unroll
  for (int j = 0; j < 4; j++) { m_i[j] = -1e30f; l_i[j] = 0.f; }

  const int nkb = q0 / 32 + 2;
  const int wq_max = q0 + w * 16 + 15;
  const float scale = 0.07216878364870322f;  // 1/sqrt(192)

  for (int kb = 0; kb < nkb; kb++) {
    const int kbase = kb * 32;
    // stage K tile and transposed V tile: 32x192 each
#pragma unroll
    for (int r = 0; r < 3; r++) {
      int v = t + 256 * r;
      int row = v / 24;
      int c8 = (v % 24) * 8;
      short8 kk = *(const short8*)&Kp[(size_t)(kbase + row) * HEAD_DIM + c8];
      *(short8*)&Ks[row][c8] = kk;
      short8 vv = *(const short8*)&Vp[(size_t)(kbase + row) * HEAD_DIM + c8];
#pragma unroll
      for (int i = 0; i < 8; i++) Vt[c8 + i][row] = vv[i];
    }
    __syncthreads();

    if (kbase <= wq_max) {  // wave-uniform skip of fully-masked blocks
      // QK^T: scores [16 q][32 k]
      f32x4 sc[2] = {};
#pragma unroll
      for (int kc = 0; kc < 2; kc++)
#pragma unroll
        for (int c = 0; c < 6; c++) {
          short8 bfr = *(const short8*)&Ks[kc * 16 + lr][c * 32 + lg * 8];
          sc[kc] = __builtin_amdgcn_mfma_f32_16x16x32_bf16(qf[c], bfr, sc[kc], 0, 0, 0);
        }

      // mask + scale + online softmax
      float p0[4], p1[4], mj[4];
#pragma unroll
      for (int j = 0; j < 4; j++) {
        int qrow = q0 + w * 16 + lg * 4 + j;
        float v0 = sc[0][j] * scale;
        float v1 = sc[1][j] * scale;
        if (kbase + lr > qrow) v0 = -1e30f;
        if (kbase + 16 + lr > qrow) v1 = -1e30f;
        p0[j] = v0; p1[j] = v1;
        float mx = fmaxf(v0, v1);
#pragma unroll
        for (int s = 1; s < 16; s <<= 1) mx = fmaxf(mx, __shfl_xor(mx, s, 64));
        mj[j] = mx;
      }
      float alpha[4];
#pragma unroll
      for (int j = 0; j < 4; j++) {
        float mn = fmaxf(m_i[j], mj[j]);
        alpha[j] = __expf(m_i[j] - mn);
        m_i[j] = mn;
        float s0 = __expf(p0[j] - mn);
        float s1 = __expf(p1[j] - mn);
        float rs = s0 + s1;
#pragma unroll
        for (int s = 1; s < 16; s <<= 1) rs += __shfl_xor(rs, s, 64);
        l_i[j] = l_i[j] * alpha[j] + rs;
        Ps[w][lg * 4 + j][lr] = f2bf(s0);
        Ps[w][lg * 4 + j][16 + lr] = f2bf(s1);
      }
#pragma unroll
      for (int d = 0; d < 12; d++)
#pragma unroll
        for (int j = 0; j < 4; j++) o[d][j] *= alpha[j];

      // PV: A = P[16][32] from per-wave LDS, B = Vt
      short8 pa = *(const short8*)&Ps[w][lr][lg * 8];
#pragma unroll
      for (int d = 0; d < 12; d++) {
        short8 vb = *(const short8*)&Vt[d * 16 + lr][lg * 8];
        o[d] = __builtin_amdgcn_mfma_f32_16x16x32_bf16(pa, vb, o[d], 0, 0, 0);
      }
    }
    __syncthreads();
  }

  // epilogue: ctx[b][q][h*Dh + d] bf16
#pragma unroll
  for (int d = 0; d < 12; d++)
#pragma unroll
    for (int j = 0; j < 4; j++) {
      int qrow = q0 + w * 16 + lg * 4 + j;
      int col = h * HEAD_DIM + d * 16 + lr;
      float val = o[d][j] / l_i[j];
      ctx[((size_t)b * SEQ + qrow) * D_MODEL + col] = f2bf(val);
    }
}

// ---------------- launch ----------------
extern "C" void kernel_launch(void* const* d_in, const int* in_sizes, int n_in,
                              void* d_out, int out_size, void* d_ws, size_t ws_size,
                              hipStream_t stream) {
  const float* X  = (const float*)d_in[0];
  const float* Wq = (const float*)d_in[1];
  const float* bq = (const float*)d_in[2];
  const float* Wk = (const float*)d_in[3];
  const float* bk = (const float*)d_in[4];
  const float* Wv = (const float*)d_in[5];
  const float* bv = (const float*)d_in[6];
  const float* Wo = (const float*)d_in[7];
  const float* bo = (const float*)d_in[8];

  char* ws = (char*)d_ws;
  const size_t XB_BYTES = (size_t)M_ROWS * D_MODEL * 2;   // 12.58 MB
  const size_t WB_BYTES = (size_t)D_MODEL * D_MODEL * 2;  // 1.18 MB

  short* Xb  = (short*)(ws);
  short* Wqb = (short*)(ws + XB_BYTES);
  short* Wkb = (short*)(ws + XB_BYTES + WB_BYTES);
  short* Wvb = (short*)(ws + XB_BYTES + 2 * WB_BYTES);
  short* Wob = (short*)(ws + XB_BYTES + 3 * WB_BYTES);
  short* Qb  = (short*)(ws + XB_BYTES + 4 * WB_BYTES);
  short* Kb  = (short*)(ws + 2 * XB_BYTES + 4 * WB_BYTES);
  short* Vb  = (short*)(ws + 3 * XB_BYTES + 4 * WB_BYTES);
  short* Cb  = (short*)(ws + 4 * XB_BYTES + 4 * WB_BYTES);

  const int n8x = M_ROWS * D_MODEL / 8;   // 786432
  const int n8w = D_MODEL * D_MODEL / 8;  // 73728
  cast_kernel<<<(n8x + 255) / 256, 256, 0, stream>>>(X, Xb, n8x);
  cast_kernel<<<(n8w + 255) / 256, 256, 0, stream>>>(Wq, Wqb, n8w);
  cast_kernel<<<(n8w + 255) / 256, 256, 0, stream>>>(Wk, Wkb, n8w);
  cast_kernel<<<(n8w + 255) / 256, 256, 0, stream>>>(Wv, Wvb, n8w);
  cast_kernel<<<(n8w + 255) / 256, 256, 0, stream>>>(Wo, Wob, n8w);

  dim3 ggrid(M_ROWS / 64, D_MODEL / 64);
  gemm_bf16<1><<<ggrid, 256, 0, stream>>>(Xb, Wqb, bq, Qb, M_ROWS, D_MODEL, D_MODEL);
  gemm_bf16<1><<<ggrid, 256, 0, stream>>>(Xb, Wkb, bk, Kb, M_ROWS, D_MODEL, D_MODEL);
  gemm_bf16<1><<<ggrid, 256, 0, stream>>>(Xb, Wvb, bv, Vb, M_ROWS, D_MODEL, D_MODEL);

  attn_kernel<<<dim3(SEQ / 64, BATCH * N_HEADS), 256, 0, stream>>>(Qb, Kb, Vb, Cb);

  gemm_bf16<0><<<ggrid, 256, 0, stream>>>(Cb, Wob, bo, d_out, M_ROWS, D_MODEL, D_MODEL);
}

// Round 3
// 161.951 us; speedup vs baseline: 3.4845x; 3.4845x over previous
//
#include <hip/hip_runtime.h>
#include <hip/hip_bf16.h>
#include <cstddef>

typedef __attribute__((ext_vector_type(8))) short short8;
typedef __attribute__((ext_vector_type(4))) float f32x4;
typedef __attribute__((ext_vector_type(4))) unsigned short u16x4;

#define D_MODEL 768
#define N_HEADS 4
#define HEAD_DIM 192
#define BATCH 4
#define SEQ 2048
#define M_ROWS (BATCH*SEQ)

__device__ __forceinline__ short f2bf(float f) {
  union { float f; unsigned u; } v; v.f = f;
  unsigned r = v.u + 0x7FFFu + ((v.u >> 16) & 1u);
  return (short)(r >> 16);
}

__device__ __forceinline__ float fexp2(float x) {
  return __builtin_amdgcn_exp2f(x);
}

__device__ __forceinline__ void gl_lds16(const void* g, void* l) {
  __builtin_amdgcn_global_load_lds(
      (const __attribute__((address_space(1))) void*)g,
      (__attribute__((address_space(3))) void*)l, 16, 0, 0);
}

// ---------------- cast fp32 -> bf16, 8 elems/thread ----------------
__global__ __launch_bounds__(256) void cast_kernel(const float* __restrict__ src,
                                                   short* __restrict__ dst, int n8) {
  int i = blockIdx.x * 256 + threadIdx.x;
  if (i >= n8) return;
  const float4* s = (const float4*)src;
  float4 a = s[2 * i], b = s[2 * i + 1];
  short8 o;
  o[0] = f2bf(a.x); o[1] = f2bf(a.y); o[2] = f2bf(a.z); o[3] = f2bf(a.w);
  o[4] = f2bf(b.x); o[5] = f2bf(b.y); o[6] = f2bf(b.z); o[7] = f2bf(b.w);
  *(short8*)(dst + (size_t)i * 8) = o;
}

// ---------------- transpose-cast W[k][n] f32 -> Wt[n][k] bf16 ----------------
__global__ __launch_bounds__(256) void wtrans(const float* __restrict__ W,
                                              short* __restrict__ Wt) {
  __shared__ float tile[32][33];
  int k0 = blockIdx.x * 32, n0 = blockIdx.y * 32;
  int tc = threadIdx.x & 31, tr = threadIdx.x >> 5;  // tr 0..7
#pragma unroll
  for (int i = 0; i < 4; i++)
    tile[tr + i * 8][tc] = W[(size_t)(k0 + tr + i * 8) * D_MODEL + n0 + tc];
  __syncthreads();
#pragma unroll
  for (int i = 0; i < 4; i++)
    Wt[(size_t)(n0 + tr + i * 8) * D_MODEL + k0 + tc] = f2bf(tile[tc][tr + i * 8]);
}

__global__ __launch_bounds__(256) void bias_concat(const float* __restrict__ a,
                                                   const float* __restrict__ b,
                                                   const float* __restrict__ c,
                                                   float* __restrict__ dst) {
  int i = blockIdx.x * 256 + threadIdx.x;
  if (i >= 3 * D_MODEL) return;
  float v = i < 768 ? a[i] : (i < 1536 ? b[i - 768] : c[i - 1536]);
  dst[i] = v;
}

// ---------------- bf16 MFMA GEMM, 128x128 tile, BK=64, global_load_lds ----------------
// MODE 1: QKV fused -> Q,K split-head [bh][s][d]; V transposed [bh][d][s]
// MODE 0: out fp32 [M][N]
template <int MODE>
__global__ __launch_bounds__(256, 4) void gemm_bf16(const short* __restrict__ A,
                                                    const short* __restrict__ Wt,
                                                    const float* __restrict__ bias,
                                                    short* __restrict__ oQ,
                                                    short* __restrict__ oK,
                                                    short* __restrict__ oV,
                                                    float* __restrict__ oF, int N) {
  __shared__ short As[128 * 64];
  __shared__ short Bs[128 * 64];
  const int K = 768;
  const int m0 = blockIdx.x * 128, n0 = blockIdx.y * 128;
  const int t = threadIdx.x, lane = t & 63, w = t >> 6;
  const int wr = w >> 1, wc = w & 1, lr = lane & 15, lg = lane >> 4;

  f32x4 acc[4][4] = {};

  for (int k0 = 0; k0 < K; k0 += 64) {
#pragma unroll
    for (int i = 0; i < 4; i++) {
      int id = w * 4 + i;
      int row = id * 8 + (lane >> 3);
      int cc = (lane & 7) ^ (row & 7);
      gl_lds16(A + (size_t)(m0 + row) * K + k0 + cc * 8, As + id * 512);
      gl_lds16(Wt + (size_t)(n0 + row) * K + k0 + cc * 8, Bs + id * 512);
    }
    __syncthreads();
#pragma unroll
    for (int kb = 0; kb < 2; kb++) {
      short8 a[4], b[4];
#pragma unroll
      for (int m = 0; m < 4; m++) {
        int row = wr * 64 + m * 16 + lr;
        a[m] = *(const short8*)&As[row * 64 + (((kb * 4 + lg) ^ (row & 7)) << 3)];
      }
#pragma unroll
      for (int n = 0; n < 4; n++) {
        int row = wc * 64 + n * 16 + lr;
        b[n] = *(const short8*)&Bs[row * 64 + (((kb * 4 + lg) ^ (row & 7)) << 3)];
      }
#pragma unroll
      for (int m = 0; m < 4; m++)
#pragma unroll
        for (int n = 0; n < 4; n++)
          acc[m][n] = __builtin_amdgcn_mfma_f32_16x16x32_bf16(a[m], b[n], acc[m][n], 0, 0, 0);
    }
    __syncthreads();
  }

  if (MODE == 0) {
#pragma unroll
    for (int m = 0; m < 4; m++)
#pragma unroll
      for (int n = 0; n < 4; n++) {
        int col = n0 + wc * 64 + n * 16 + lr;
        float bv = bias[col];
#pragma unroll
        for (int r = 0; r < 4; r++) {
          int row = m0 + wr * 64 + m * 16 + lg * 4 + r;
          oF[(size_t)row * N + col] = acc[m][n][r] + bv;
        }
      }
  } else {
    const int bb = m0 >> 11;
#pragma unroll
    for (int m = 0; m < 4; m++) {
      int s0 = (m0 & (SEQ - 1)) + wr * 64 + m * 16 + lg * 4;
#pragma unroll
      for (int n = 0; n < 4; n++) {
        int col = n0 + wc * 64 + n * 16 + lr;
        int seg = col / 768;
        int d = col - seg * 768;
        int h = d / HEAD_DIM, dd = d - h * HEAD_DIM;
        int bh = bb * N_HEADS + h;
        float bv = bias[col];
        if (seg < 2) {
          short* dst = seg == 0 ? oQ : oK;
#pragma unroll
          for (int r = 0; r < 4; r++)
            dst[((size_t)bh * SEQ + s0 + r) * HEAD_DIM + dd] = f2bf(acc[m][n][r] + bv);
        } else {
          u16x4 pk;
#pragma unroll
          for (int r = 0; r < 4; r++) pk[r] = (unsigned short)f2bf(acc[m][n][r] + bv);
          *(u16x4*)&oV[((size_t)bh * HEAD_DIM + dd) * SEQ + s0] = pk;
        }
      }
    }
  }
}

// ---------------- staging helper for attention (K + transposed V) ----------------
__device__ __forceinline__ void stage_kv(const short* Kp, const short* Vp, int kbase,
                                         short* KsB, short* VsB, int w, int lane) {
#pragma unroll
  for (int i = 0; i < 6; i++) {
    int id = w * 6 + i;
    int o16 = id * 64 + lane;
    int row = o16 / 24, cc0 = o16 - row * 24;
    int cc = cc0 ^ (row & 7);
    gl_lds16(Kp + (size_t)(kbase + row) * HEAD_DIM + cc * 8, KsB + id * 512);
  }
#pragma unroll
  for (int i = 0; i < 6; i++) {
    int id = w * 6 + i;
    int o16 = id * 64 + lane;
    int row = o16 >> 3, cc = (o16 & 7) ^ (row & 7);
    gl_lds16(Vp + (size_t)row * SEQ + kbase + cc * 8, VsB + id * 512);
  }
}

// ---------------- flash causal attention, paired q-tiles ----------------
// Q,K: [bh][s][192]; V: [bh][192][s] (pre-transposed); ctx: bf16 [b][s][768]
__global__ __launch_bounds__(256, 1) void attn_kernel(const short* __restrict__ Q,
                                                      const short* __restrict__ Kg,
                                                      const short* __restrict__ Vt,
                                                      short* __restrict__ ctx) {
  __shared__ short Ks[2][64 * 192];
  __shared__ short Vs[2][192 * 64];
  __shared__ short Ps[4][16 * 72];

  const int n = blockIdx.x;            // 0..255
  const int slot = n >> 3;             // 0..31
  const int bh = (n & 7) * 2 + (slot >> 4);
  const int p = slot & 15;             // pair index
  const int b = bh >> 2, h = bh & 3;
  const short* Qp = Q + (size_t)bh * SEQ * HEAD_DIM;
  const short* Kp = Kg + (size_t)bh * SEQ * HEAD_DIM;
  const short* Vp = Vt + (size_t)bh * HEAD_DIM * SEQ;
  const int t = threadIdx.x, lane = t & 63, w = t >> 6;
  const int lr = lane & 15, lg = lane >> 4;
  const float scale2 = 0.07216878364870322f * 1.4426950408889634f;  // 1/sqrt(192)*log2e

  for (int pass = 0; pass < 2; pass++) {
    const int qt = (pass == 0) ? p : 31 - p;
    const int nkb = qt + 1;
    const int qrow_w = qt * 64 + w * 16;

    short8 qf[6];
#pragma unroll
    for (int c = 0; c < 6; c++)
      qf[c] = *(const short8*)&Qp[(size_t)(qrow_w + lr) * HEAD_DIM + c * 32 + lg * 8];

    f32x4 o[12] = {};
    float m2[4], l[4], alpha[4];
#pragma unroll
    for (int j = 0; j < 4; j++) { m2[j] = -3.0e38f; l[j] = 0.f; }

    stage_kv(Kp, Vp, 0, Ks[0], Vs[0], w, lane);

    for (int kb = 0; kb < nkb; kb++) {
      const int cur = kb & 1;
      const int kbase = kb * 64;
      if (kb + 1 < nkb) {
        stage_kv(Kp, Vp, kbase + 64, Ks[cur ^ 1], Vs[cur ^ 1], w, lane);
        asm volatile("s_waitcnt vmcnt(12)" ::: "memory");
      } else {
        asm volatile("s_waitcnt vmcnt(0)" ::: "memory");
      }
      __builtin_amdgcn_s_barrier();
      asm volatile("" ::: "memory");

      const short* Kc = Ks[cur];
      const short* Vc = Vs[cur];

      // QK^T: [16 q][64 k]
      f32x4 sc[4] = {};
#pragma unroll
      for (int kc = 0; kc < 4; kc++) {
        int row = kc * 16 + lr;
        int rsw = row & 7;
#pragma unroll
        for (int c = 0; c < 6; c++) {
          short8 bfr = *(const short8*)&Kc[row * 192 + (((c * 4 + lg) ^ rsw) << 3)];
          sc[kc] = __builtin_amdgcn_mfma_f32_16x16x32_bf16(qf[c], bfr, sc[kc], 0, 0, 0);
        }
      }

      // online softmax in exp2 domain
#pragma unroll
      for (int j = 0; j < 4; j++) {
        int qrow = qrow_w + lg * 4 + j;
        float v[4];
#pragma unroll
        for (int kc = 0; kc < 4; kc++) {
          int col = kbase + kc * 16 + lr;
          v[kc] = (col <= qrow) ? sc[kc][j] * scale2 : -3.0e38f;
        }
        float mx = fmaxf(fmaxf(v[0], v[1]), fmaxf(v[2], v[3]));
#pragma unroll
        for (int s2 = 1; s2 < 16; s2 <<= 1) mx = fmaxf(mx, __shfl_xor(mx, s2, 64));
        float mn = fmaxf(m2[j], mx);
        alpha[j] = fexp2(m2[j] - mn);
        m2[j] = mn;
        float rs = 0.f;
#pragma unroll
        for (int kc = 0; kc < 4; kc++) {
          float e = fexp2(v[kc] - mn);
          rs += e;
          Ps[w][(lg * 4 + j) * 72 + kc * 16 + lr] = f2bf(e);
        }
#pragma unroll
        for (int s2 = 1; s2 < 16; s2 <<= 1) rs += __shfl_xor(rs, s2, 64);
        l[j] = l[j] * alpha[j] + rs;
      }
#pragma unroll
      for (int dd = 0; dd < 12; dd++)
#pragma unroll
        for (int j = 0; j < 4; j++) o[dd][j] *= alpha[j];

      // PV
#pragma unroll
      for (int kb32 = 0; kb32 < 2; kb32++) {
        short8 pa = *(const short8*)&Ps[w][lr * 72 + kb32 * 32 + lg * 8];
#pragma unroll
        for (int dd = 0; dd < 12; dd++) {
          int row = dd * 16 + lr;
          short8 vb = *(const short8*)&Vc[row * 64 + (((kb32 * 4 + lg) ^ (row & 7)) << 3)];
          o[dd] = __builtin_amdgcn_mfma_f32_16x16x32_bf16(pa, vb, o[dd], 0, 0, 0);
        }
      }
      asm volatile("" ::: "memory");
      __builtin_amdgcn_s_barrier();  // protect cur buffer before next prefetch overwrites
    }

    // epilogue
#pragma unroll
    for (int j = 0; j < 4; j++) {
      int qrow = qrow_w + lg * 4 + j;
      float rl = 1.0f / l[j];
#pragma unroll
      for (int dd = 0; dd < 12; dd++) {
        int col = h * HEAD_DIM + dd * 16 + lr;
        ctx[((size_t)b * SEQ + qrow) * D_MODEL + col] = f2bf(o[dd][j] * rl);
      }
    }
    __builtin_amdgcn_s_barrier();
  }
}

// ---------------- launch ----------------
extern "C" void kernel_launch(void* const* d_in, const int* in_sizes, int n_in,
                              void* d_out, int out_size, void* d_ws, size_t ws_size,
                              hipStream_t stream) {
  const float* X  = (const float*)d_in[0];
  const float* Wq = (const float*)d_in[1];
  const float* bq = (const float*)d_in[2];
  const float* Wk = (const float*)d_in[3];
  const float* bk = (const float*)d_in[4];
  const float* Wv = (const float*)d_in[5];
  const float* bv = (const float*)d_in[6];
  const float* Wo = (const float*)d_in[7];
  const float* bo = (const float*)d_in[8];

  char* ws = (char*)d_ws;
  const size_t XB = (size_t)M_ROWS * D_MODEL * 2;       // 12.58 MB
  const size_t WQKV = (size_t)3 * D_MODEL * D_MODEL * 2; // 3.54 MB
  const size_t WB = (size_t)D_MODEL * D_MODEL * 2;       // 1.18 MB

  short* Xb    = (short*)(ws);
  short* Wqkvt = (short*)(ws + XB);
  short* Wot   = (short*)(ws + XB + WQKV);
  float* bqkv  = (float*)(ws + XB + WQKV + WB);
  short* Qb    = (short*)(ws + XB + WQKV + WB + 12288);
  short* Kb    = (short*)(ws + XB + WQKV + WB + 12288 + XB);
  short* Vtb   = (short*)(ws + XB + WQKV + WB + 12288 + 2 * XB);
  short* Cb    = (short*)(ws + XB + WQKV + WB + 12288 + 3 * XB);

  const int n8x = M_ROWS * D_MODEL / 8;
  cast_kernel<<<(n8x + 255) / 256, 256, 0, stream>>>(X, Xb, n8x);
  dim3 tg(24, 24);
  wtrans<<<tg, 256, 0, stream>>>(Wq, Wqkvt);
  wtrans<<<tg, 256, 0, stream>>>(Wk, Wqkvt + (size_t)768 * 768);
  wtrans<<<tg, 256, 0, stream>>>(Wv, Wqkvt + (size_t)2 * 768 * 768);
  wtrans<<<tg, 256, 0, stream>>>(Wo, Wot);
  bias_concat<<<9, 256, 0, stream>>>(bq, bk, bv, bqkv);

  gemm_bf16<1><<<dim3(M_ROWS / 128, 2304 / 128), 256, 0, stream>>>(
      Xb, Wqkvt, bqkv, Qb, Kb, Vtb, nullptr, 2304);

  attn_kernel<<<256, 256, 0, stream>>>(Qb, Kb, Vtb, Cb);

  gemm_bf16<0><<<dim3(M_ROWS / 128, 768 / 128), 256, 0, stream>>>(
      Cb, Wot, bo, nullptr, nullptr, nullptr, (float*)d_out, 768);
}

// Round 4
// 154.362 us; speedup vs baseline: 3.6558x; 1.0492x over previous
//
#include <hip/hip_runtime.h>
#include <hip/hip_bf16.h>
#include <cstddef>

typedef __attribute__((ext_vector_type(8))) short short8;
typedef __attribute__((ext_vector_type(4))) float f32x4;
typedef __attribute__((ext_vector_type(16))) float f32x16;
typedef __attribute__((ext_vector_type(4))) unsigned short u16x4;

#define D_MODEL 768
#define N_HEADS 4
#define HEAD_DIM 192
#define BATCH 4
#define SEQ 2048
#define M_ROWS (BATCH*SEQ)

__device__ __forceinline__ short f2bf(float f) {
  union { float f; unsigned u; } v; v.f = f;
  unsigned r = v.u + 0x7FFFu + ((v.u >> 16) & 1u);
  return (short)(r >> 16);
}

__device__ __forceinline__ float fexp2(float x) {
  return __builtin_amdgcn_exp2f(x);
}

__device__ __forceinline__ void gl_lds16(const void* g, void* l) {
  __builtin_amdgcn_global_load_lds(
      (const __attribute__((address_space(1))) void*)g,
      (__attribute__((address_space(3))) void*)l, 16, 0, 0);
}

// ---------------- cast fp32 -> bf16, 8 elems/thread ----------------
__global__ __launch_bounds__(256) void cast_kernel(const float* __restrict__ src,
                                                   short* __restrict__ dst, int n8) {
  int i = blockIdx.x * 256 + threadIdx.x;
  if (i >= n8) return;
  const float4* s = (const float4*)src;
  float4 a = s[2 * i], b = s[2 * i + 1];
  short8 o;
  o[0] = f2bf(a.x); o[1] = f2bf(a.y); o[2] = f2bf(a.z); o[3] = f2bf(a.w);
  o[4] = f2bf(b.x); o[5] = f2bf(b.y); o[6] = f2bf(b.z); o[7] = f2bf(b.w);
  *(short8*)(dst + (size_t)i * 8) = o;
}

// ---------------- transpose-cast W[k][n] f32 -> Wt[n][k] bf16 ----------------
__global__ __launch_bounds__(256) void wtrans(const float* __restrict__ W,
                                              short* __restrict__ Wt) {
  __shared__ float tile[32][33];
  int k0 = blockIdx.x * 32, n0 = blockIdx.y * 32;
  int tc = threadIdx.x & 31, tr = threadIdx.x >> 5;
#pragma unroll
  for (int i = 0; i < 4; i++)
    tile[tr + i * 8][tc] = W[(size_t)(k0 + tr + i * 8) * D_MODEL + n0 + tc];
  __syncthreads();
#pragma unroll
  for (int i = 0; i < 4; i++)
    Wt[(size_t)(n0 + tr + i * 8) * D_MODEL + k0 + tc] = f2bf(tile[tc][tr + i * 8]);
}

__global__ __launch_bounds__(256) void bias_concat(const float* __restrict__ a,
                                                   const float* __restrict__ b,
                                                   const float* __restrict__ c,
                                                   float* __restrict__ dst) {
  int i = blockIdx.x * 256 + threadIdx.x;
  if (i >= 3 * D_MODEL) return;
  float v = i < 768 ? a[i] : (i < 1536 ? b[i - 768] : c[i - 1536]);
  dst[i] = v;
}

// ---------------- bf16 MFMA GEMM, 128x128 tile, BK=64, global_load_lds ----------------
template <int MODE>
__global__ __launch_bounds__(256, 4) void gemm_bf16(const short* __restrict__ A,
                                                    const short* __restrict__ Wt,
                                                    const float* __restrict__ bias,
                                                    short* __restrict__ oQ,
                                                    short* __restrict__ oK,
                                                    short* __restrict__ oV,
                                                    float* __restrict__ oF, int N) {
  __shared__ short As[128 * 64];
  __shared__ short Bs[128 * 64];
  const int K = 768;
  const int m0 = blockIdx.x * 128, n0 = blockIdx.y * 128;
  const int t = threadIdx.x, lane = t & 63, w = t >> 6;
  const int wr = w >> 1, wc = w & 1, lr = lane & 15, lg = lane >> 4;

  f32x4 acc[4][4] = {};

  for (int k0 = 0; k0 < K; k0 += 64) {
#pragma unroll
    for (int i = 0; i < 4; i++) {
      int id = w * 4 + i;
      int row = id * 8 + (lane >> 3);
      int cc = (lane & 7) ^ (row & 7);
      gl_lds16(A + (size_t)(m0 + row) * K + k0 + cc * 8, As + id * 512);
      gl_lds16(Wt + (size_t)(n0 + row) * K + k0 + cc * 8, Bs + id * 512);
    }
    __syncthreads();
#pragma unroll
    for (int kb = 0; kb < 2; kb++) {
      short8 a[4], b[4];
#pragma unroll
      for (int m = 0; m < 4; m++) {
        int row = wr * 64 + m * 16 + lr;
        a[m] = *(const short8*)&As[row * 64 + (((kb * 4 + lg) ^ (row & 7)) << 3)];
      }
#pragma unroll
      for (int n = 0; n < 4; n++) {
        int row = wc * 64 + n * 16 + lr;
        b[n] = *(const short8*)&Bs[row * 64 + (((kb * 4 + lg) ^ (row & 7)) << 3)];
      }
#pragma unroll
      for (int m = 0; m < 4; m++)
#pragma unroll
        for (int n = 0; n < 4; n++)
          acc[m][n] = __builtin_amdgcn_mfma_f32_16x16x32_bf16(a[m], b[n], acc[m][n], 0, 0, 0);
    }
    __syncthreads();
  }

  if (MODE == 0) {
#pragma unroll
    for (int m = 0; m < 4; m++)
#pragma unroll
      for (int n = 0; n < 4; n++) {
        int col = n0 + wc * 64 + n * 16 + lr;
        float bv = bias[col];
#pragma unroll
        for (int r = 0; r < 4; r++) {
          int row = m0 + wr * 64 + m * 16 + lg * 4 + r;
          oF[(size_t)row * N + col] = acc[m][n][r] + bv;
        }
      }
  } else {
    const int bb = m0 >> 11;
#pragma unroll
    for (int m = 0; m < 4; m++) {
      int s0 = (m0 & (SEQ - 1)) + wr * 64 + m * 16 + lg * 4;
#pragma unroll
      for (int n = 0; n < 4; n++) {
        int col = n0 + wc * 64 + n * 16 + lr;
        int seg = col / 768;
        int d = col - seg * 768;
        int h = d / HEAD_DIM, dd = d - h * HEAD_DIM;
        int bh = bb * N_HEADS + h;
        float bv = bias[col];
        if (seg < 2) {
          short* dst = seg == 0 ? oQ : oK;
#pragma unroll
          for (int r = 0; r < 4; r++)
            dst[((size_t)bh * SEQ + s0 + r) * HEAD_DIM + dd] = f2bf(acc[m][n][r] + bv);
        } else {
          u16x4 pk;
#pragma unroll
          for (int r = 0; r < 4; r++) pk[r] = (unsigned short)f2bf(acc[m][n][r] + bv);
          *(u16x4*)&oV[((size_t)bh * HEAD_DIM + dd) * SEQ + s0] = pk;
        }
      }
    }
  }
}

// ---------------- staging helper for attention (K + transposed V) ----------------
__device__ __forceinline__ void stage_kv(const short* Kp, const short* Vp, int kbase,
                                         short* KsB, short* VsB, int w, int lane) {
#pragma unroll
  for (int i = 0; i < 6; i++) {
    int id = w * 6 + i;
    int o16 = id * 64 + lane;
    int row = o16 / 24, cc0 = o16 - row * 24;
    int cc = cc0 ^ (row & 7);
    gl_lds16(Kp + (size_t)(kbase + row) * HEAD_DIM + cc * 8, KsB + id * 512);
  }
#pragma unroll
  for (int i = 0; i < 6; i++) {
    int id = w * 6 + i;
    int o16 = id * 64 + lane;
    int row = o16 >> 3, cc = (o16 & 7) ^ (row & 7);
    gl_lds16(Vp + (size_t)row * SEQ + kbase + cc * 8, VsB + id * 512);
  }
}

// ---------------- flash causal attention: 32x32 frags, swapped QK^T ----------------
// 4 waves: wq = q-half (32 rows), wk = k-half (32 of KVBLK=64). Paired q-tiles.
// Q,K: [bh][s][192]; V: [bh][192][s]; ctx: bf16 [b][s][768]
__global__ __launch_bounds__(256, 1) void attn_kernel(const short* __restrict__ Q,
                                                      const short* __restrict__ Kg,
                                                      const short* __restrict__ Vt,
                                                      short* __restrict__ ctx) {
  __shared__ short Ks[2][64 * 192];
  __shared__ short Vs[2][192 * 64];
  float* obuf = (float*)&Vs[0][0];    // 2*32*192 f32 = 49152 B (reused post-loop)
  float* mlbuf = (float*)&Ks[0][0];   // 2*64 f32

  const int n = blockIdx.x;            // 0..255
  const int slot = n >> 3;
  const int bh = (n & 7) * 2 + (slot >> 4);
  const int p = slot & 15;
  const int b = bh >> 2, head = bh & 3;
  const short* Qp = Q + (size_t)bh * SEQ * HEAD_DIM;
  const short* Kp = Kg + (size_t)bh * SEQ * HEAD_DIM;
  const short* Vp = Vt + (size_t)bh * HEAD_DIM * SEQ;
  const int t = threadIdx.x, lane = t & 63, w = t >> 6;
  const int wq = w >> 1, wk = w & 1;
  const int l31 = lane & 31, hl = lane >> 5;
  const float scale2 = 0.07216878364870322f * 1.4426950408889634f;  // 1/sqrt(192)*log2e

  for (int pass = 0; pass < 2; pass++) {
    const int qt = pass ? 31 - p : p;
    const int nkb = qt + 1;
    const int q0w = qt * 64 + wq * 32;
    const int qlane = q0w + l31;

    stage_kv(Kp, Vp, 0, Ks[0], Vs[0], w, lane);

    // Q^T B-fragments from global: lane holds q = qlane, d = c*16 + hl*8 + i
    short8 qf[12];
#pragma unroll
    for (int c = 0; c < 12; c++)
      qf[c] = *(const short8*)&Qp[(size_t)qlane * HEAD_DIM + c * 16 + hl * 8];

    f32x16 oacc[6];
#pragma unroll
    for (int d = 0; d < 6; d++) oacc[d] = 0.f;
    float m = -3.0e38f, lsum = 0.f;

    for (int kb = 0; kb < nkb; kb++) {
      const int cur = kb & 1;
      const int kbase = kb * 64;
      if (kb + 1 < nkb) {
        stage_kv(Kp, Vp, kbase + 64, Ks[cur ^ 1], Vs[cur ^ 1], w, lane);
        asm volatile("s_waitcnt vmcnt(12)" ::: "memory");
      } else {
        asm volatile("s_waitcnt vmcnt(0)" ::: "memory");
      }
      __builtin_amdgcn_s_barrier();
      asm volatile("" ::: "memory");

      if (kbase + wk * 32 <= q0w + 31) {  // wave-uniform skip
        const short* KcB = Ks[cur];
        const short* VcB = Vs[cur];

        // S^T[32k][32q] = K * Q^T  (lane: q = l31; k in regs)
        f32x16 sacc = 0.f;
        const int krow = wk * 32 + l31;
        const int krb = krow * 192;
        const int kswz = (krow & 7) << 3;
#pragma unroll
        for (int c = 0; c < 12; c++) {
          short8 kf = *(const short8*)&KcB[krb + ((c * 16 + hl * 8) ^ kswz)];
          sacc = __builtin_amdgcn_mfma_f32_32x32x16_bf16(kf, qf[c], sacc, 0, 0, 0);
        }

        // in-lane softmax over this wave's 32-k slice
        float s[16];
        const bool need_mask = (kbase + wk * 32 + 31) > q0w;
        const int kb0 = kbase + wk * 32 + 4 * hl;
#pragma unroll
        for (int r = 0; r < 16; r++) {
          float v = sacc[r] * scale2;
          if (need_mask) {
            int kg = kb0 + (r & 3) + 8 * (r >> 2);
            if (kg > qlane) v = -3.0e38f;
          }
          s[r] = v;
        }
        float mx = s[0];
#pragma unroll
        for (int r = 1; r < 16; r++) mx = fmaxf(mx, s[r]);
        mx = fmaxf(mx, __shfl_xor(mx, 32, 64));
        if (!__all(mx <= m + 8.0f)) {  // defer-max
          float mn = fmaxf(m, mx);
          float al = fexp2(m - mn);
          m = mn;
          lsum *= al;
#pragma unroll
          for (int d = 0; d < 6; d++) oacc[d] *= al;
        }
        float pr[16];
        float rs = 0.f;
#pragma unroll
        for (int r = 0; r < 16; r++) {
          pr[r] = fexp2(s[r] - m);
          rs += pr[r];
        }
        rs += __shfl_xor(rs, 32, 64);
        lsum += rs;

        // pack P to bf16 pairs, exchange halves, build PV B-frags
        unsigned pk[8], ex[8];
#pragma unroll
        for (int j = 0; j < 8; j++) {
          unsigned r0;
          asm("v_cvt_pk_bf16_f32 %0, %1, %2" : "=v"(r0) : "v"(pr[2 * j]), "v"(pr[2 * j + 1]));
          pk[j] = r0;
        }
#pragma unroll
        for (int j = 0; j < 8; j++) ex[j] = __shfl_xor((int)pk[j], 32, 64);
        union { unsigned u[4]; short8 s8; } f0, f1;
        f0.u[0] = hl ? ex[2] : pk[0];
        f0.u[1] = hl ? ex[3] : pk[1];
        f0.u[2] = hl ? pk[2] : ex[0];
        f0.u[3] = hl ? pk[3] : ex[1];
        f1.u[0] = hl ? ex[6] : pk[4];
        f1.u[1] = hl ? ex[7] : pk[5];
        f1.u[2] = hl ? pk[6] : ex[4];
        f1.u[3] = hl ? pk[7] : ex[5];

        // O^T[32d][32q] += V^T * P^T   (lane: q = l31 -> alpha/l per-lane)
#pragma unroll
        for (int db = 0; db < 6; db++) {
          const int vrow = db * 32 + l31;
          const int vrb = vrow * 64;
          const int vswz = (vrow & 7) << 3;
          short8 va = *(const short8*)&VcB[vrb + ((wk * 32 + hl * 8) ^ vswz)];
          oacc[db] = __builtin_amdgcn_mfma_f32_32x32x16_bf16(va, f0.s8, oacc[db], 0, 0, 0);
          short8 vb = *(const short8*)&VcB[vrb + ((wk * 32 + 16 + hl * 8) ^ vswz)];
          oacc[db] = __builtin_amdgcn_mfma_f32_32x32x16_bf16(vb, f1.s8, oacc[db], 0, 0, 0);
        }
      }
      asm volatile("" ::: "memory");
      __builtin_amdgcn_s_barrier();
    }

    // ---- k-split merge (waves wk=1 -> wk=0) + epilogue ----
    __syncthreads();
    if (wk == 1) {
      if (lane < 32) {
        mlbuf[wq * 64 + lane] = m;
        mlbuf[wq * 64 + 32 + lane] = lsum;
      }
#pragma unroll
      for (int db = 0; db < 6; db++)
#pragma unroll
        for (int g = 0; g < 4; g++) {
          int d = db * 32 + 8 * g + 4 * hl;
          f32x4 vv;
          vv[0] = oacc[db][4 * g];
          vv[1] = oacc[db][4 * g + 1];
          vv[2] = oacc[db][4 * g + 2];
          vv[3] = oacc[db][4 * g + 3];
          *(f32x4*)&obuf[(wq * 32 + l31) * 192 + (d ^ ((l31 & 7) << 2))] = vv;
        }
    }
    __syncthreads();
    if (wk == 0) {
      float m1 = mlbuf[wq * 64 + l31];
      float l1 = mlbuf[wq * 64 + 32 + l31];
      float ms = fmaxf(m, m1);
      float a0 = fexp2(m - ms), a1 = fexp2(m1 - ms);
      float lt = lsum * a0 + l1 * a1;
      float rl = 1.0f / lt;
#pragma unroll
      for (int db = 0; db < 6; db++)
#pragma unroll
        for (int g = 0; g < 4; g++) {
          int d = db * 32 + 8 * g + 4 * hl;
          f32x4 rd = *(const f32x4*)&obuf[(wq * 32 + l31) * 192 + (d ^ ((l31 & 7) << 2))];
          u16x4 pkk;
#pragma unroll
          for (int r2 = 0; r2 < 4; r2++) {
            float v = (oacc[db][4 * g + r2] * a0 + rd[r2] * a1) * rl;
            pkk[r2] = (unsigned short)f2bf(v);
          }
          *(u16x4*)&ctx[((size_t)b * SEQ + qlane) * D_MODEL + head * HEAD_DIM + d] = pkk;
        }
    }
    __syncthreads();
  }
}

// ---------------- launch ----------------
extern "C" void kernel_launch(void* const* d_in, const int* in_sizes, int n_in,
                              void* d_out, int out_size, void* d_ws, size_t ws_size,
                              hipStream_t stream) {
  const float* X  = (const float*)d_in[0];
  const float* Wq = (const float*)d_in[1];
  const float* bq = (const float*)d_in[2];
  const float* Wk = (const float*)d_in[3];
  const float* bk = (const float*)d_in[4];
  const float* Wv = (const float*)d_in[5];
  const float* bv = (const float*)d_in[6];
  const float* Wo = (const float*)d_in[7];
  const float* bo = (const float*)d_in[8];

  char* ws = (char*)d_ws;
  const size_t XB = (size_t)M_ROWS * D_MODEL * 2;
  const size_t WQKV = (size_t)3 * D_MODEL * D_MODEL * 2;
  const size_t WB = (size_t)D_MODEL * D_MODEL * 2;

  short* Xb    = (short*)(ws);
  short* Wqkvt = (short*)(ws + XB);
  short* Wot   = (short*)(ws + XB + WQKV);
  float* bqkv  = (float*)(ws + XB + WQKV + WB);
  short* Qb    = (short*)(ws + XB + WQKV + WB + 12288);
  short* Kb    = (short*)(ws + XB + WQKV + WB + 12288 + XB);
  short* Vtb   = (short*)(ws + XB + WQKV + WB + 12288 + 2 * XB);
  short* Cb    = (short*)(ws + XB + WQKV + WB + 12288 + 3 * XB);

  const int n8x = M_ROWS * D_MODEL / 8;
  cast_kernel<<<(n8x + 255) / 256, 256, 0, stream>>>(X, Xb, n8x);
  dim3 tg(24, 24);
  wtrans<<<tg, 256, 0, stream>>>(Wq, Wqkvt);
  wtrans<<<tg, 256, 0, stream>>>(Wk, Wqkvt + (size_t)768 * 768);
  wtrans<<<tg, 256, 0, stream>>>(Wv, Wqkvt + (size_t)2 * 768 * 768);
  wtrans<<<tg, 256, 0, stream>>>(Wo, Wot);
  bias_concat<<<9, 256, 0, stream>>>(bq, bk, bv, bqkv);

  gemm_bf16<1><<<dim3(M_ROWS / 128, 2304 / 128), 256, 0, stream>>>(
      Xb, Wqkvt, bqkv, Qb, Kb, Vtb, nullptr, 2304);

  attn_kernel<<<256, 256, 0, stream>>>(Qb, Kb, Vtb, Cb);

  gemm_bf16<0><<<dim3(M_ROWS / 128, 768 / 128), 256, 0, stream>>>(
      Cb, Wot, bo, nullptr, nullptr, nullptr, (float*)d_out, 768);
}

// Round 5
// 144.672 us; speedup vs baseline: 3.9007x; 1.0670x over previous
//
#include <hip/hip_runtime.h>
#include <hip/hip_bf16.h>
#include <cstddef>

typedef __attribute__((ext_vector_type(8))) short short8;
typedef __attribute__((ext_vector_type(4))) float f32x4;
typedef __attribute__((ext_vector_type(16))) float f32x16;
typedef __attribute__((ext_vector_type(4))) unsigned short u16x4;

#define D_MODEL 768
#define N_HEADS 4
#define HEAD_DIM 192
#define BATCH 4
#define SEQ 2048
#define M_ROWS (BATCH*SEQ)

__device__ __forceinline__ short f2bf(float f) {
  union { float f; unsigned u; } v; v.f = f;
  unsigned r = v.u + 0x7FFFu + ((v.u >> 16) & 1u);
  return (short)(r >> 16);
}

__device__ __forceinline__ float fexp2(float x) {
  return __builtin_amdgcn_exp2f(x);
}

__device__ __forceinline__ void gl_lds16(const void* g, void* l) {
  __builtin_amdgcn_global_load_lds(
      (const __attribute__((address_space(1))) void*)g,
      (__attribute__((address_space(3))) void*)l, 16, 0, 0);
}

// ---------------- cast fp32 -> bf16, 8 elems/thread ----------------
__global__ __launch_bounds__(256) void cast_kernel(const float* __restrict__ src,
                                                   short* __restrict__ dst, int n8) {
  int i = blockIdx.x * 256 + threadIdx.x;
  if (i >= n8) return;
  const float4* s = (const float4*)src;
  float4 a = s[2 * i], b = s[2 * i + 1];
  short8 o;
  o[0] = f2bf(a.x); o[1] = f2bf(a.y); o[2] = f2bf(a.z); o[3] = f2bf(a.w);
  o[4] = f2bf(b.x); o[5] = f2bf(b.y); o[6] = f2bf(b.z); o[7] = f2bf(b.w);
  *(short8*)(dst + (size_t)i * 8) = o;
}

// ---------------- transpose-cast W[k][n] f32 -> Wt[n][k] bf16 ----------------
__global__ __launch_bounds__(256) void wtrans(const float* __restrict__ W,
                                              short* __restrict__ Wt) {
  __shared__ float tile[32][33];
  int k0 = blockIdx.x * 32, n0 = blockIdx.y * 32;
  int tc = threadIdx.x & 31, tr = threadIdx.x >> 5;
#pragma unroll
  for (int i = 0; i < 4; i++)
    tile[tr + i * 8][tc] = W[(size_t)(k0 + tr + i * 8) * D_MODEL + n0 + tc];
  __syncthreads();
#pragma unroll
  for (int i = 0; i < 4; i++)
    Wt[(size_t)(n0 + tr + i * 8) * D_MODEL + k0 + tc] = f2bf(tile[tc][tr + i * 8]);
}

__global__ __launch_bounds__(256) void bias_concat(const float* __restrict__ a,
                                                   const float* __restrict__ b,
                                                   const float* __restrict__ c,
                                                   float* __restrict__ dst) {
  int i = blockIdx.x * 256 + threadIdx.x;
  if (i >= 3 * D_MODEL) return;
  float v = i < 768 ? a[i] : (i < 1536 ? b[i - 768] : c[i - 1536]);
  dst[i] = v;
}

// ---------------- bf16 MFMA GEMM, 128x128 tile, BK=64, global_load_lds ----------------
template <int MODE>
__global__ __launch_bounds__(256, 4) void gemm_bf16(const short* __restrict__ A,
                                                    const short* __restrict__ Wt,
                                                    const float* __restrict__ bias,
                                                    short* __restrict__ oQ,
                                                    short* __restrict__ oK,
                                                    short* __restrict__ oV,
                                                    float* __restrict__ oF, int N) {
  __shared__ short As[128 * 64];
  __shared__ short Bs[128 * 64];
  const int K = 768;
  const int m0 = blockIdx.x * 128, n0 = blockIdx.y * 128;
  const int t = threadIdx.x, lane = t & 63, w = t >> 6;
  const int wr = w >> 1, wc = w & 1, lr = lane & 15, lg = lane >> 4;

  f32x4 acc[4][4] = {};

  for (int k0 = 0; k0 < K; k0 += 64) {
#pragma unroll
    for (int i = 0; i < 4; i++) {
      int id = w * 4 + i;
      int row = id * 8 + (lane >> 3);
      int cc = (lane & 7) ^ (row & 7);
      gl_lds16(A + (size_t)(m0 + row) * K + k0 + cc * 8, As + id * 512);
      gl_lds16(Wt + (size_t)(n0 + row) * K + k0 + cc * 8, Bs + id * 512);
    }
    __syncthreads();
#pragma unroll
    for (int kb = 0; kb < 2; kb++) {
      short8 a[4], b[4];
#pragma unroll
      for (int m = 0; m < 4; m++) {
        int row = wr * 64 + m * 16 + lr;
        a[m] = *(const short8*)&As[row * 64 + (((kb * 4 + lg) ^ (row & 7)) << 3)];
      }
#pragma unroll
      for (int n = 0; n < 4; n++) {
        int row = wc * 64 + n * 16 + lr;
        b[n] = *(const short8*)&Bs[row * 64 + (((kb * 4 + lg) ^ (row & 7)) << 3)];
      }
#pragma unroll
      for (int m = 0; m < 4; m++)
#pragma unroll
        for (int n = 0; n < 4; n++)
          acc[m][n] = __builtin_amdgcn_mfma_f32_16x16x32_bf16(a[m], b[n], acc[m][n], 0, 0, 0);
    }
    __syncthreads();
  }

  if (MODE == 0) {
#pragma unroll
    for (int m = 0; m < 4; m++)
#pragma unroll
      for (int n = 0; n < 4; n++) {
        int col = n0 + wc * 64 + n * 16 + lr;
        float bv = bias[col];
#pragma unroll
        for (int r = 0; r < 4; r++) {
          int row = m0 + wr * 64 + m * 16 + lg * 4 + r;
          oF[(size_t)row * N + col] = acc[m][n][r] + bv;
        }
      }
  } else {
    const int bb = m0 >> 11;
#pragma unroll
    for (int m = 0; m < 4; m++) {
      int s0 = (m0 & (SEQ - 1)) + wr * 64 + m * 16 + lg * 4;
#pragma unroll
      for (int n = 0; n < 4; n++) {
        int col = n0 + wc * 64 + n * 16 + lr;
        int seg = col / 768;
        int d = col - seg * 768;
        int h = d / HEAD_DIM, dd = d - h * HEAD_DIM;
        int bh = bb * N_HEADS + h;
        float bv = bias[col];
        if (seg < 2) {
          short* dst = seg == 0 ? oQ : oK;
#pragma unroll
          for (int r = 0; r < 4; r++)
            dst[((size_t)bh * SEQ + s0 + r) * HEAD_DIM + dd] = f2bf(acc[m][n][r] + bv);
        } else {
          u16x4 pk;
#pragma unroll
          for (int r = 0; r < 4; r++) pk[r] = (unsigned short)f2bf(acc[m][n][r] + bv);
          *(u16x4*)&oV[((size_t)bh * HEAD_DIM + dd) * SEQ + s0] = pk;
        }
      }
    }
  }
}

// ---------------- staging helper for attention (K + transposed V) ----------------
__device__ __forceinline__ void stage_kv(const short* Kp, const short* Vp, int kbase,
                                         short* KsB, short* VsB, int w, int lane) {
#pragma unroll
  for (int i = 0; i < 6; i++) {
    int id = w * 6 + i;
    int o16 = id * 64 + lane;
    int row = o16 / 24, cc0 = o16 - row * 24;
    int cc = cc0 ^ (row & 7);
    gl_lds16(Kp + (size_t)(kbase + row) * HEAD_DIM + cc * 8, KsB + id * 512);
  }
#pragma unroll
  for (int i = 0; i < 6; i++) {
    int id = w * 6 + i;
    int o16 = id * 64 + lane;
    int row = o16 >> 3, cc = (o16 & 7) ^ (row & 7);
    gl_lds16(Vp + (size_t)row * SEQ + kbase + cc * 8, VsB + id * 512);
  }
}

// ---------------- flash causal attention: 32x32 frags, swapped QK^T ----------------
// 512 blocks (one q-tile of 64 rows each), 4 waves = 2 q-split x 2 k-split.
// Single-buffered K/V LDS (48KB) -> 2 blocks/CU, 2 waves/SIMD.
// Q,K: [bh][s][192]; V: [bh][192][s]; ctx: bf16 [b][s][768]
__global__ __launch_bounds__(256, 2) void attn_kernel(const short* __restrict__ Q,
                                                      const short* __restrict__ Kg,
                                                      const short* __restrict__ Vt,
                                                      short* __restrict__ ctx) {
  __shared__ short smem[64 * 192 + 192 * 64];  // K tile | V tile (49152 B)
  __shared__ float mlbuf[128];
  short* Ks = smem;
  short* Vs = smem + 64 * 192;
  float* obuf = (float*)smem;  // merge buffer, reuses K+V region after k-loop

  // LPT-ish ordering: first 256 blocks get qt 31..16, second 256 get qt 0..15
  const int i = blockIdx.x;
  int bh, qt;
  if (i < 256) { bh = i & 15; qt = 31 - (i >> 4); }
  else         { int j = i - 256; bh = j & 15; qt = j >> 4; }

  const int b = bh >> 2, head = bh & 3;
  const short* Qp = Q + (size_t)bh * SEQ * HEAD_DIM;
  const short* Kp = Kg + (size_t)bh * SEQ * HEAD_DIM;
  const short* Vp = Vt + (size_t)bh * HEAD_DIM * SEQ;
  const int t = threadIdx.x, lane = t & 63, w = t >> 6;
  const int wq = w >> 1, wk = w & 1;
  const int l31 = lane & 31, hl = lane >> 5;
  const float scale2 = 0.07216878364870322f * 1.4426950408889634f;  // 1/sqrt(192)*log2e

  const int nkb = qt + 1;
  const int q0w = qt * 64 + wq * 32;
  const int qlane = q0w + l31;

  // Q^T B-fragments from global: lane holds q = qlane, d = c*16 + hl*8 + i
  short8 qf[12];
#pragma unroll
  for (int c = 0; c < 12; c++)
    qf[c] = *(const short8*)&Qp[(size_t)qlane * HEAD_DIM + c * 16 + hl * 8];

  f32x16 oacc[6];
#pragma unroll
  for (int d = 0; d < 6; d++) oacc[d] = 0.f;
  float m = -3.0e38f, lsum = 0.f;

  for (int kb = 0; kb < nkb; kb++) {
    const int kbase = kb * 64;
    stage_kv(Kp, Vp, kbase, Ks, Vs, w, lane);
    asm volatile("s_waitcnt vmcnt(0)" ::: "memory");
    __builtin_amdgcn_s_barrier();
    asm volatile("" ::: "memory");

    if (kbase + wk * 32 <= q0w + 31) {  // wave-uniform skip
      // S^T[32k][32q] = K * Q^T  (lane: q = l31; k in regs)
      f32x16 sacc = 0.f;
      const int krow = wk * 32 + l31;
      const int krb = krow * 192;
      const int kswz = (krow & 7) << 3;
      __builtin_amdgcn_s_setprio(1);
#pragma unroll
      for (int c = 0; c < 12; c++) {
        short8 kf = *(const short8*)&Ks[krb + ((c * 16 + hl * 8) ^ kswz)];
        sacc = __builtin_amdgcn_mfma_f32_32x32x16_bf16(kf, qf[c], sacc, 0, 0, 0);
      }
      __builtin_amdgcn_s_setprio(0);

      // in-lane softmax over this wave's 32-k slice
      float s[16];
      const bool need_mask = (kbase + wk * 32 + 31) > q0w;
      const int kb0 = kbase + wk * 32 + 4 * hl;
#pragma unroll
      for (int r = 0; r < 16; r++) {
        float v = sacc[r] * scale2;
        if (need_mask) {
          int kg = kb0 + (r & 3) + 8 * (r >> 2);
          if (kg > qlane) v = -3.0e38f;
        }
        s[r] = v;
      }
      float mx = s[0];
#pragma unroll
      for (int r = 1; r < 16; r++) mx = fmaxf(mx, s[r]);
      mx = fmaxf(mx, __shfl_xor(mx, 32, 64));
      if (!__all(mx <= m + 8.0f)) {  // defer-max
        float mn = fmaxf(m, mx);
        float al = fexp2(m - mn);
        m = mn;
        lsum *= al;
#pragma unroll
        for (int d = 0; d < 6; d++) oacc[d] *= al;
      }
      float pr[16];
      float rs = 0.f;
#pragma unroll
      for (int r = 0; r < 16; r++) {
        pr[r] = fexp2(s[r] - m);
        rs += pr[r];
      }
      rs += __shfl_xor(rs, 32, 64);
      lsum += rs;

      // pack P to bf16 pairs, exchange halves, build PV B-frags
      unsigned pk[8], ex[8];
#pragma unroll
      for (int j = 0; j < 8; j++) {
        unsigned r0;
        asm("v_cvt_pk_bf16_f32 %0, %1, %2" : "=v"(r0) : "v"(pr[2 * j]), "v"(pr[2 * j + 1]));
        pk[j] = r0;
      }
#pragma unroll
      for (int j = 0; j < 8; j++) ex[j] = __shfl_xor((int)pk[j], 32, 64);
      union { unsigned u[4]; short8 s8; } f0, f1;
      f0.u[0] = hl ? ex[2] : pk[0];
      f0.u[1] = hl ? ex[3] : pk[1];
      f0.u[2] = hl ? pk[2] : ex[0];
      f0.u[3] = hl ? pk[3] : ex[1];
      f1.u[0] = hl ? ex[6] : pk[4];
      f1.u[1] = hl ? ex[7] : pk[5];
      f1.u[2] = hl ? pk[6] : ex[4];
      f1.u[3] = hl ? pk[7] : ex[5];

      // O^T[32d][32q] += V^T * P^T   (lane: q = l31 -> alpha/l per-lane)
      __builtin_amdgcn_s_setprio(1);
#pragma unroll
      for (int db = 0; db < 6; db++) {
        const int vrow = db * 32 + l31;
        const int vrb = vrow * 64;
        const int vswz = (vrow & 7) << 3;
        short8 va = *(const short8*)&Vs[vrb + ((wk * 32 + hl * 8) ^ vswz)];
        oacc[db] = __builtin_amdgcn_mfma_f32_32x32x16_bf16(va, f0.s8, oacc[db], 0, 0, 0);
        short8 vb = *(const short8*)&Vs[vrb + ((wk * 32 + 16 + hl * 8) ^ vswz)];
        oacc[db] = __builtin_amdgcn_mfma_f32_32x32x16_bf16(vb, f1.s8, oacc[db], 0, 0, 0);
      }
      __builtin_amdgcn_s_setprio(0);
    }
    asm volatile("" ::: "memory");
    __builtin_amdgcn_s_barrier();  // all waves done reading before next stage
  }

  // ---- k-split merge (waves wk=1 -> wk=0) + epilogue ----
  __syncthreads();
  if (wk == 1) {
    if (lane < 32) {
      mlbuf[wq * 64 + lane] = m;
      mlbuf[wq * 64 + 32 + lane] = lsum;
    }
#pragma unroll
    for (int db = 0; db < 6; db++)
#pragma unroll
      for (int g = 0; g < 4; g++) {
        int d = db * 32 + 8 * g + 4 * hl;
        f32x4 vv;
        vv[0] = oacc[db][4 * g];
        vv[1] = oacc[db][4 * g + 1];
        vv[2] = oacc[db][4 * g + 2];
        vv[3] = oacc[db][4 * g + 3];
        *(f32x4*)&obuf[(wq * 32 + l31) * 192 + (d ^ ((l31 & 7) << 2))] = vv;
      }
  }
  __syncthreads();
  if (wk == 0) {
    float m1 = mlbuf[wq * 64 + l31];
    float l1 = mlbuf[wq * 64 + 32 + l31];
    float ms = fmaxf(m, m1);
    float a0 = fexp2(m - ms), a1 = fexp2(m1 - ms);
    float lt = lsum * a0 + l1 * a1;
    float rl = 1.0f / lt;
#pragma unroll
    for (int db = 0; db < 6; db++)
#pragma unroll
      for (int g = 0; g < 4; g++) {
        int d = db * 32 + 8 * g + 4 * hl;
        f32x4 rd = *(const f32x4*)&obuf[(wq * 32 + l31) * 192 + (d ^ ((l31 & 7) << 2))];
        u16x4 pkk;
#pragma unroll
        for (int r2 = 0; r2 < 4; r2++) {
          float v = (oacc[db][4 * g + r2] * a0 + rd[r2] * a1) * rl;
          pkk[r2] = (unsigned short)f2bf(v);
        }
        *(u16x4*)&ctx[((size_t)b * SEQ + qlane) * D_MODEL + head * HEAD_DIM + d] = pkk;
      }
  }
}

// ---------------- launch ----------------
extern "C" void kernel_launch(void* const* d_in, const int* in_sizes, int n_in,
                              void* d_out, int out_size, void* d_ws, size_t ws_size,
                              hipStream_t stream) {
  const float* X  = (const float*)d_in[0];
  const float* Wq = (const float*)d_in[1];
  const float* bq = (const float*)d_in[2];
  const float* Wk = (const float*)d_in[3];
  const float* bk = (const float*)d_in[4];
  const float* Wv = (const float*)d_in[5];
  const float* bv = (const float*)d_in[6];
  const float* Wo = (const float*)d_in[7];
  const float* bo = (const float*)d_in[8];

  char* ws = (char*)d_ws;
  const size_t XB = (size_t)M_ROWS * D_MODEL * 2;
  const size_t WQKV = (size_t)3 * D_MODEL * D_MODEL * 2;
  const size_t WB = (size_t)D_MODEL * D_MODEL * 2;

  short* Xb    = (short*)(ws);
  short* Wqkvt = (short*)(ws + XB);
  short* Wot   = (short*)(ws + XB + WQKV);
  float* bqkv  = (float*)(ws + XB + WQKV + WB);
  short* Qb    = (short*)(ws + XB + WQKV + WB + 12288);
  short* Kb    = (short*)(ws + XB + WQKV + WB + 12288 + XB);
  short* Vtb   = (short*)(ws + XB + WQKV + WB + 12288 + 2 * XB);
  short* Cb    = (short*)(ws + XB + WQKV + WB + 12288 + 3 * XB);

  const int n8x = M_ROWS * D_MODEL / 8;
  cast_kernel<<<(n8x + 255) / 256, 256, 0, stream>>>(X, Xb, n8x);
  dim3 tg(24, 24);
  wtrans<<<tg, 256, 0, stream>>>(Wq, Wqkvt);
  wtrans<<<tg, 256, 0, stream>>>(Wk, Wqkvt + (size_t)768 * 768);
  wtrans<<<tg, 256, 0, stream>>>(Wv, Wqkvt + (size_t)2 * 768 * 768);
  wtrans<<<tg, 256, 0, stream>>>(Wo, Wot);
  bias_concat<<<9, 256, 0, stream>>>(bq, bk, bv, bqkv);

  gemm_bf16<1><<<dim3(M_ROWS / 128, 2304 / 128), 256, 0, stream>>>(
      Xb, Wqkvt, bqkv, Qb, Kb, Vtb, nullptr, 2304);

  attn_kernel<<<512, 256, 0, stream>>>(Qb, Kb, Vtb, Cb);

  gemm_bf16<0><<<dim3(M_ROWS / 128, 768 / 128), 256, 0, stream>>>(
      Cb, Wot, bo, nullptr, nullptr, nullptr, (float*)d_out, 768);
}